// Round 1
// baseline (39163.660 us; speedup 1.0000x reference)
//
#include <hip/hip_runtime.h>
#include <cmath>

// RNN: T=2048, B=64, I=H=512, fp32.
// Phase 1: xw = x @ W_ih^T + (b_ih+b_hh)  -> written into d_out [T*B, H]
// Phase 2: 64 WGs (1 per batch), W_hh resident in VGPRs (256 fp32/thread),
//          h in LDS, 2048 steps with 2 __syncthreads each, in-place on d_out.

#define SEQ_T 2048
#define BATCH 64
#define KDIM 512
#define HDIM 512

// ================= Phase 1: tiled fp32 GEMM (A row-major, B^T layout) ======
#define BM 128
#define BN 64
#define BK 32
#define LDA_T (BM + 4)  // k-major transposed A tile, padded (16B-aligned rows, bank-spread)
#define LDB_T (BN + 4)

__global__ __launch_bounds__(256) void xw_gemm(const float* __restrict__ x,
                                               const float* __restrict__ Wih,
                                               const float* __restrict__ bih,
                                               const float* __restrict__ bhh,
                                               float* __restrict__ out) {
  __shared__ float As[BK * LDA_T];
  __shared__ float Bs[BK * LDB_T];
  const int tid = threadIdx.x;
  const int nb = blockIdx.x & 7;   // N/BN = 8
  const int mb = blockIdx.x >> 3;  // M/BM = 1024
  const int m0 = mb * BM;
  const int n0 = nb * BN;
  const int tx = tid & 15;  // n-dir: 4 cols each
  const int ty = tid >> 4;  // m-dir: 8 rows each

  float acc[8][4];
#pragma unroll
  for (int i = 0; i < 8; ++i)
#pragma unroll
    for (int j = 0; j < 4; ++j) acc[i][j] = 0.f;

  for (int k0 = 0; k0 < KDIM; k0 += BK) {
    // stage A tile (128x32) transposed -> As[k][m]
#pragma unroll
    for (int p = 0; p < 4; ++p) {
      int idx = tid + p * 256;
      int r = idx >> 3, c = idx & 7;
      float4 a = *(const float4*)(x + (size_t)(m0 + r) * KDIM + k0 + c * 4);
      As[(c * 4 + 0) * LDA_T + r] = a.x;
      As[(c * 4 + 1) * LDA_T + r] = a.y;
      As[(c * 4 + 2) * LDA_T + r] = a.z;
      As[(c * 4 + 3) * LDA_T + r] = a.w;
    }
    // stage B tile (64x32) transposed -> Bs[k][n]
#pragma unroll
    for (int p = 0; p < 2; ++p) {
      int idx = tid + p * 256;
      int r = idx >> 3, c = idx & 7;
      float4 bv = *(const float4*)(Wih + (size_t)(n0 + r) * KDIM + k0 + c * 4);
      Bs[(c * 4 + 0) * LDB_T + r] = bv.x;
      Bs[(c * 4 + 1) * LDB_T + r] = bv.y;
      Bs[(c * 4 + 2) * LDB_T + r] = bv.z;
      Bs[(c * 4 + 3) * LDB_T + r] = bv.w;
    }
    __syncthreads();
#pragma unroll
    for (int kk = 0; kk < BK; ++kk) {
      float4 a0 = *(const float4*)(As + kk * LDA_T + ty * 8);
      float4 a1 = *(const float4*)(As + kk * LDA_T + ty * 8 + 4);
      float4 b0 = *(const float4*)(Bs + kk * LDB_T + tx * 4);
      float am[8] = {a0.x, a0.y, a0.z, a0.w, a1.x, a1.y, a1.z, a1.w};
      float bn_[4] = {b0.x, b0.y, b0.z, b0.w};
#pragma unroll
      for (int i = 0; i < 8; ++i)
#pragma unroll
        for (int j = 0; j < 4; ++j) acc[i][j] = fmaf(am[i], bn_[j], acc[i][j]);
    }
    __syncthreads();
  }

  float4 bi = *(const float4*)(bih + n0 + tx * 4);
  float4 bh = *(const float4*)(bhh + n0 + tx * 4);
  const float b0 = bi.x + bh.x, b1 = bi.y + bh.y, b2 = bi.z + bh.z, b3 = bi.w + bh.w;
#pragma unroll
  for (int i = 0; i < 8; ++i) {
    float4 v = make_float4(acc[i][0] + b0, acc[i][1] + b1, acc[i][2] + b2, acc[i][3] + b3);
    *(float4*)(out + (size_t)(m0 + ty * 8 + i) * HDIM + n0 + tx * 4) = v;
  }
}

// ================= Phase 2: recurrence, 1 WG per batch element =============
// thread tid: group g = tid>>2 owns rows j0=g, j1=g+256; kq = tid&3 owns
// k in [kq*128, kq*128+128). W_hh rows held in 256 VGPRs (wa/wb float4[32]).
// h stored in LDS as 4 padded quarters (132 floats each) so the 4 kq
// broadcast-streams hit disjoint bank groups.
__global__ __launch_bounds__(1024) void rnn_scan(const float* __restrict__ Whh,
                                                 float* __restrict__ io /* xw in, h out */) {
  __shared__ float h_pad[4 * 132];
  const int tid = threadIdx.x;
  const int b = blockIdx.x;
  const int g = tid >> 2;  // 0..255
  const int kq = tid & 3;
  const int j0 = g, j1 = g + 256;
  const int k0 = kq * 128;

  // load W rows into registers (one-time; W is L2/L3-resident after first WG)
  float4 wa[32], wb[32];
#pragma unroll
  for (int u = 0; u < 32; ++u) {
    wa[u] = *(const float4*)(Whh + (size_t)j0 * HDIM + k0 + u * 4);
    wb[u] = *(const float4*)(Whh + (size_t)j1 * HDIM + k0 + u * 4);
  }

  if (tid < 512) h_pad[(tid >> 7) * 132 + (tid & 127)] = 0.0f;
  __syncthreads();

  const float* hq = &h_pad[kq * 132];

  for (int t = 0; t < SEQ_T; ++t) {
    float* row = io + ((size_t)t * BATCH + b) * HDIM;
    // prefetch this step's input-projection values (hidden under the dot loop)
    float uin = 0.f;
    if (kq == 0) uin = row[j0];
    else if (kq == 1) uin = row[j1];

    // 8 independent FMA chains (4 per row) to cover FMA latency
    float a0x = 0.f, a0y = 0.f, a0z = 0.f, a0w = 0.f;
    float a1x = 0.f, a1y = 0.f, a1z = 0.f, a1w = 0.f;
#pragma unroll
    for (int u = 0; u < 32; ++u) {
      float4 h4 = *(const float4*)(hq + u * 4);  // quad-broadcast, bank-disjoint per kq
      a0x = fmaf(wa[u].x, h4.x, a0x);
      a0y = fmaf(wa[u].y, h4.y, a0y);
      a0z = fmaf(wa[u].z, h4.z, a0z);
      a0w = fmaf(wa[u].w, h4.w, a0w);
      a1x = fmaf(wb[u].x, h4.x, a1x);
      a1y = fmaf(wb[u].y, h4.y, a1y);
      a1z = fmaf(wb[u].z, h4.z, a1z);
      a1w = fmaf(wb[u].w, h4.w, a1w);
    }
    float acc0 = (a0x + a0y) + (a0z + a0w);
    float acc1 = (a1x + a1y) + (a1z + a1w);
    // combine the 4 k-quarters within each lane-quad
    acc0 += __shfl_xor(acc0, 1);
    acc0 += __shfl_xor(acc0, 2);
    acc1 += __shfl_xor(acc1, 1);
    acc1 += __shfl_xor(acc1, 2);

    __syncthreads();  // everyone done reading h for this step

    if (kq == 0) {
      float hn = tanhf(uin + acc0);
      h_pad[(j0 >> 7) * 132 + (j0 & 127)] = hn;
      row[j0] = hn;
    } else if (kq == 1) {
      float hn = tanhf(uin + acc1);
      h_pad[(j1 >> 7) * 132 + (j1 & 127)] = hn;
      row[j1] = hn;
    }

    __syncthreads();  // h for step t visible to all
  }
}

extern "C" void kernel_launch(void* const* d_in, const int* in_sizes, int n_in,
                              void* d_out, int out_size, void* d_ws, size_t ws_size,
                              hipStream_t stream) {
  const float* x = (const float*)d_in[0];
  const float* Wih = (const float*)d_in[1];
  const float* Whh = (const float*)d_in[2];
  const float* bih = (const float*)d_in[3];
  const float* bhh = (const float*)d_in[4];
  float* out = (float*)d_out;

  const int M = SEQ_T * BATCH;  // 131072
  dim3 g1((M / BM) * (HDIM / BN));  // 1024*8 = 8192 blocks
  xw_gemm<<<g1, 256, 0, stream>>>(x, Wih, bih, bhh, out);

  rnn_scan<<<BATCH, 1024, 0, stream>>>(Whh, out);
}

// Round 2
// 37551.538 us; speedup vs baseline: 1.0429x; 1.0429x over previous
//
#include <hip/hip_runtime.h>
#include <cmath>

// RNN: T=2048, B=64, I=H=512, fp32.
// Phase 1: xw = x @ W_ih^T + (b_ih+b_hh)  -> written into d_out [T*B, H]
// Phase 2: 64 WGs (1 per batch). W_hh resident in 256 *named* VGPRs/thread
//          (4 rows x 64-k-slice). h double-buffered in LDS, 1 barrier/step.
//          Reduce over 8 k-slices: xor1/xor2 via DPP quad_perm (VALU) +
//          one __shfl_xor(32). k-slice lanes at lane-bits {0,1,5}.

#define SEQ_T 2048
#define BATCH 64
#define KDIM 512
#define HDIM 512

// ================= Phase 1: tiled fp32 GEMM (A row-major, B^T layout) ======
#define BM 128
#define BN 64
#define BK 32
#define LDA_T (BM + 4)
#define LDB_T (BN + 4)

__global__ __launch_bounds__(256) void xw_gemm(const float* __restrict__ x,
                                               const float* __restrict__ Wih,
                                               const float* __restrict__ bih,
                                               const float* __restrict__ bhh,
                                               float* __restrict__ out) {
  __shared__ float As[BK * LDA_T];
  __shared__ float Bs[BK * LDB_T];
  const int tid = threadIdx.x;
  const int nb = blockIdx.x & 7;
  const int mb = blockIdx.x >> 3;
  const int m0 = mb * BM;
  const int n0 = nb * BN;
  const int tx = tid & 15;
  const int ty = tid >> 4;

  float acc[8][4];
#pragma unroll
  for (int i = 0; i < 8; ++i)
#pragma unroll
    for (int j = 0; j < 4; ++j) acc[i][j] = 0.f;

  for (int k0 = 0; k0 < KDIM; k0 += BK) {
#pragma unroll
    for (int p = 0; p < 4; ++p) {
      int idx = tid + p * 256;
      int r = idx >> 3, c = idx & 7;
      float4 a = *(const float4*)(x + (size_t)(m0 + r) * KDIM + k0 + c * 4);
      As[(c * 4 + 0) * LDA_T + r] = a.x;
      As[(c * 4 + 1) * LDA_T + r] = a.y;
      As[(c * 4 + 2) * LDA_T + r] = a.z;
      As[(c * 4 + 3) * LDA_T + r] = a.w;
    }
#pragma unroll
    for (int p = 0; p < 2; ++p) {
      int idx = tid + p * 256;
      int r = idx >> 3, c = idx & 7;
      float4 bv = *(const float4*)(Wih + (size_t)(n0 + r) * KDIM + k0 + c * 4);
      Bs[(c * 4 + 0) * LDB_T + r] = bv.x;
      Bs[(c * 4 + 1) * LDB_T + r] = bv.y;
      Bs[(c * 4 + 2) * LDB_T + r] = bv.z;
      Bs[(c * 4 + 3) * LDB_T + r] = bv.w;
    }
    __syncthreads();
#pragma unroll
    for (int kk = 0; kk < BK; ++kk) {
      float4 a0 = *(const float4*)(As + kk * LDA_T + ty * 8);
      float4 a1 = *(const float4*)(As + kk * LDA_T + ty * 8 + 4);
      float4 b0 = *(const float4*)(Bs + kk * LDB_T + tx * 4);
      float am[8] = {a0.x, a0.y, a0.z, a0.w, a1.x, a1.y, a1.z, a1.w};
      float bn_[4] = {b0.x, b0.y, b0.z, b0.w};
#pragma unroll
      for (int i = 0; i < 8; ++i)
#pragma unroll
        for (int j = 0; j < 4; ++j) acc[i][j] = fmaf(am[i], bn_[j], acc[i][j]);
    }
    __syncthreads();
  }

  float4 bi = *(const float4*)(bih + n0 + tx * 4);
  float4 bh = *(const float4*)(bhh + n0 + tx * 4);
  const float b0 = bi.x + bh.x, b1 = bi.y + bh.y, b2 = bi.z + bh.z, b3 = bi.w + bh.w;
#pragma unroll
  for (int i = 0; i < 8; ++i) {
    float4 v = make_float4(acc[i][0] + b0, acc[i][1] + b1, acc[i][2] + b2, acc[i][3] + b3);
    *(float4*)(out + (size_t)(m0 + ty * 8 + i) * HDIM + n0 + tx * 4) = v;
  }
}

// ================= Phase 2: recurrence =====================================
// thread -> lane l = tid&63, wave w = tid>>6
//   k-slice  s (0..7)  = (l&3) | ((l>>3)&4)      lane bits {0,1,5}
//   row-group g (0..127)= ((l>>2)&7) | (w<<3)    lane bits {2,3,4} + wave
// owns rows j_r = g + 128*r (r=0..3), k in [64s, 64s+64).
// W in 64 NAMED float4 registers (no alloca -> no scratch).

#define REPU(M) M(0) M(1) M(2) M(3) M(4) M(5) M(6) M(7) \
                M(8) M(9) M(10) M(11) M(12) M(13) M(14) M(15)

#define DECLW(r, u) float4 w##r##_##u = *(const float4*)(Wr##r + 4 * u);
#define DECLW0(u) DECLW(0, u)
#define DECLW1(u) DECLW(1, u)
#define DECLW2(u) DECLW(2, u)
#define DECLW3(u) DECLW(3, u)

#define DOTU(u)                                                      \
  {                                                                  \
    float4 h4 = *(const float4*)(hc + 4 * u);                        \
    accA0 = fmaf(w0_##u.x, h4.x, accA0);                             \
    accA0 = fmaf(w0_##u.y, h4.y, accA0);                             \
    accB0 = fmaf(w0_##u.z, h4.z, accB0);                             \
    accB0 = fmaf(w0_##u.w, h4.w, accB0);                             \
    accA1 = fmaf(w1_##u.x, h4.x, accA1);                             \
    accA1 = fmaf(w1_##u.y, h4.y, accA1);                             \
    accB1 = fmaf(w1_##u.z, h4.z, accB1);                             \
    accB1 = fmaf(w1_##u.w, h4.w, accB1);                             \
    accA2 = fmaf(w2_##u.x, h4.x, accA2);                             \
    accA2 = fmaf(w2_##u.y, h4.y, accA2);                             \
    accB2 = fmaf(w2_##u.z, h4.z, accB2);                             \
    accB2 = fmaf(w2_##u.w, h4.w, accB2);                             \
    accA3 = fmaf(w3_##u.x, h4.x, accA3);                             \
    accA3 = fmaf(w3_##u.y, h4.y, accA3);                             \
    accB3 = fmaf(w3_##u.z, h4.z, accB3);                             \
    accB3 = fmaf(w3_##u.w, h4.w, accB3);                             \
  }

// quad_perm DPP: xor1 -> [1,0,3,2] = 0xB1 (177), xor2 -> [2,3,0,1] = 0x4E (78)
#define XOR_DPP(v, ctrl)                                              \
  (v + __int_as_float(__builtin_amdgcn_mov_dpp(__float_as_int(v),     \
                                               ctrl, 0xf, 0xf, true)))

__global__ __launch_bounds__(1024, 4) void rnn_scan(const float* __restrict__ Whh,
                                                    float* __restrict__ io) {
  __shared__ __align__(16) float hbuf[2][8 * 68];  // slices padded 64->68
  const int tid = threadIdx.x;
  const int b = blockIdx.x;
  const int l = tid & 63;
  const int w = tid >> 6;
  const int s = (l & 3) | ((l >> 3) & 4);
  const int g = ((l >> 2) & 7) | (w << 3);

  const float* Wr0 = Whh + (size_t)(g)*KDIM + 64 * s;
  const float* Wr1 = Whh + (size_t)(g + 128) * KDIM + 64 * s;
  const float* Wr2 = Whh + (size_t)(g + 256) * KDIM + 64 * s;
  const float* Wr3 = Whh + (size_t)(g + 384) * KDIM + 64 * s;
  REPU(DECLW0)
  REPU(DECLW1)
  REPU(DECLW2)
  REPU(DECLW3)

  if (tid < 512) hbuf[0][(tid >> 6) * 68 + (tid & 63)] = 0.0f;
  __syncthreads();

  const bool writer = (s < 4);
  const int jw = g + 128 * s;                      // valid row only when writer
  const int widx = ((jw >> 6) * 68) + (jw & 63);   // LDS slot of row jw
  float* iorow = io + (size_t)b * HDIM;

  for (int t = 0; t < SEQ_T; ++t) {
    const float* hc = &hbuf[t & 1][s * 68];
    float* nx = &hbuf[(t & 1) ^ 1][0];

    float uin = 0.0f;
    if (writer) uin = iorow[jw];

    float accA0 = 0.f, accB0 = 0.f, accA1 = 0.f, accB1 = 0.f;
    float accA2 = 0.f, accB2 = 0.f, accA3 = 0.f, accB3 = 0.f;
    REPU(DOTU)

    float t0 = accA0 + accB0;
    float t1 = accA1 + accB1;
    float t2 = accA2 + accB2;
    float t3 = accA3 + accB3;
    t0 = XOR_DPP(t0, 177); t0 = XOR_DPP(t0, 78); t0 += __shfl_xor(t0, 32);
    t1 = XOR_DPP(t1, 177); t1 = XOR_DPP(t1, 78); t1 += __shfl_xor(t1, 32);
    t2 = XOR_DPP(t2, 177); t2 = XOR_DPP(t2, 78); t2 += __shfl_xor(t2, 32);
    t3 = XOR_DPP(t3, 177); t3 = XOR_DPP(t3, 78); t3 += __shfl_xor(t3, 32);

    if (writer) {
      float tsel = (s == 0) ? t0 : (s == 1) ? t1 : (s == 2) ? t2 : t3;
      float z = uin + tsel;
      float e = __expf(2.0f * z);
      float hn = 1.0f - 2.0f / (e + 1.0f);  // tanh(z)
      iorow[jw] = hn;
      nx[widx] = hn;
    }
    iorow += (size_t)BATCH * HDIM;
    __syncthreads();
  }
}

extern "C" void kernel_launch(void* const* d_in, const int* in_sizes, int n_in,
                              void* d_out, int out_size, void* d_ws, size_t ws_size,
                              hipStream_t stream) {
  const float* x = (const float*)d_in[0];
  const float* Wih = (const float*)d_in[1];
  const float* Whh = (const float*)d_in[2];
  const float* bih = (const float*)d_in[3];
  const float* bhh = (const float*)d_in[4];
  float* out = (float*)d_out;

  const int M = SEQ_T * BATCH;
  dim3 g1((M / BM) * (HDIM / BN));
  xw_gemm<<<g1, 256, 0, stream>>>(x, Wih, bih, bhh, out);

  rnn_scan<<<BATCH, 1024, 0, stream>>>(Whh, out);
}

// Round 3
// 8636.593 us; speedup vs baseline: 4.5346x; 4.3480x over previous
//
#include <hip/hip_runtime.h>
#include <cmath>

// RNN: T=2048, B=64, I=H=512, fp32 in/out.
// Phase 0: w_prep   — convert streamed 24/64 of W_hh cols to fp16 into d_ws.
// Phase 1: xw_gemm  — xw = x @ W_ih^T + (b_ih+b_hh) -> d_out [T*B, H] (fp32).
// Phase 2: rnn_scan — 64 WGs (1/batch) x 512 thr. Per thread: 8 rows x 64-col
//          slice of W_hh as fp16; 40 cols static in 160 named VGPRs, 24 cols
//          streamed from L2 each step. v_dot2_f32_f16 inner product, h in LDS
//          (fp16, padded slices), DPP quad-perm k-reduce + LDS partial table.

#define SEQ_T 2048
#define BATCH 64
#define KDIM 512
#define HDIM 512

typedef _Float16 h2v __attribute__((ext_vector_type(2)));

static __device__ __forceinline__ float fdot2f(float wv, float hv, float acc) {
  return __builtin_amdgcn_fdot2(__builtin_bit_cast(h2v, wv),
                                __builtin_bit_cast(h2v, hv), acc, false);
}
static __device__ __forceinline__ float pkh(float a, float b) {
  return __builtin_bit_cast(float, __builtin_amdgcn_cvt_pkrtz(a, b));
}
static __device__ __forceinline__ float4 pk4(float4 a, float4 b) {
  return make_float4(pkh(a.x, a.y), pkh(a.z, a.w), pkh(b.x, b.y), pkh(b.z, b.w));
}

// ================= Phase 0: prep streamed-W fp16 layout [c][w][l][r] ========
__global__ __launch_bounds__(256) void w_prep(const float* __restrict__ Whh,
                                              float4* __restrict__ ws) {
  int v = blockIdx.x * 256 + threadIdx.x;  // 12288 total
  int r = v & 7, l = (v >> 3) & 63, w = (v >> 9) & 7, c = v >> 12;
  int s = l & 7, g = (l >> 3) | (w << 3);
  int j = g + 64 * r;
  const float* p = Whh + (size_t)j * KDIM + 64 * s + 40 + 8 * c;
  float4 a = *(const float4*)(p);
  float4 b = *(const float4*)(p + 4);
  ws[v] = pk4(a, b);
}

// ================= Phase 1: tiled fp32 GEMM (unchanged) =====================
#define BM 128
#define BN 64
#define BK 32
#define LDA_T (BM + 4)
#define LDB_T (BN + 4)

__global__ __launch_bounds__(256) void xw_gemm(const float* __restrict__ x,
                                               const float* __restrict__ Wih,
                                               const float* __restrict__ bih,
                                               const float* __restrict__ bhh,
                                               float* __restrict__ out) {
  __shared__ float As[BK * LDA_T];
  __shared__ float Bs[BK * LDB_T];
  const int tid = threadIdx.x;
  const int nb = blockIdx.x & 7;
  const int mb = blockIdx.x >> 3;
  const int m0 = mb * BM;
  const int n0 = nb * BN;
  const int tx = tid & 15;
  const int ty = tid >> 4;

  float acc[8][4];
#pragma unroll
  for (int i = 0; i < 8; ++i)
#pragma unroll
    for (int j = 0; j < 4; ++j) acc[i][j] = 0.f;

  for (int k0 = 0; k0 < KDIM; k0 += BK) {
#pragma unroll
    for (int p = 0; p < 4; ++p) {
      int idx = tid + p * 256;
      int r = idx >> 3, c = idx & 7;
      float4 a = *(const float4*)(x + (size_t)(m0 + r) * KDIM + k0 + c * 4);
      As[(c * 4 + 0) * LDA_T + r] = a.x;
      As[(c * 4 + 1) * LDA_T + r] = a.y;
      As[(c * 4 + 2) * LDA_T + r] = a.z;
      As[(c * 4 + 3) * LDA_T + r] = a.w;
    }
#pragma unroll
    for (int p = 0; p < 2; ++p) {
      int idx = tid + p * 256;
      int r = idx >> 3, c = idx & 7;
      float4 bv = *(const float4*)(Wih + (size_t)(n0 + r) * KDIM + k0 + c * 4);
      Bs[(c * 4 + 0) * LDB_T + r] = bv.x;
      Bs[(c * 4 + 1) * LDB_T + r] = bv.y;
      Bs[(c * 4 + 2) * LDB_T + r] = bv.z;
      Bs[(c * 4 + 3) * LDB_T + r] = bv.w;
    }
    __syncthreads();
#pragma unroll
    for (int kk = 0; kk < BK; ++kk) {
      float4 a0 = *(const float4*)(As + kk * LDA_T + ty * 8);
      float4 a1 = *(const float4*)(As + kk * LDA_T + ty * 8 + 4);
      float4 b0 = *(const float4*)(Bs + kk * LDB_T + tx * 4);
      float am[8] = {a0.x, a0.y, a0.z, a0.w, a1.x, a1.y, a1.z, a1.w};
      float bn_[4] = {b0.x, b0.y, b0.z, b0.w};
#pragma unroll
      for (int i = 0; i < 8; ++i)
#pragma unroll
        for (int j = 0; j < 4; ++j) acc[i][j] = fmaf(am[i], bn_[j], acc[i][j]);
    }
    __syncthreads();
  }

  float4 bi = *(const float4*)(bih + n0 + tx * 4);
  float4 bh = *(const float4*)(bhh + n0 + tx * 4);
  const float b0 = bi.x + bh.x, b1 = bi.y + bh.y, b2 = bi.z + bh.z, b3 = bi.w + bh.w;
#pragma unroll
  for (int i = 0; i < 8; ++i) {
    float4 v = make_float4(acc[i][0] + b0, acc[i][1] + b1, acc[i][2] + b2, acc[i][3] + b3);
    *(float4*)(out + (size_t)(m0 + ty * 8 + i) * HDIM + n0 + tx * 4) = v;
  }
}

// ================= Phase 2: recurrence ======================================
// lane l: slice s = l&7 (cols [64s,64s+64)); g = (l>>3)|(w<<3); rows g+64r.
// LDS: hbuf[2] (8 slices x 144 B fp16, conflict-free) + P (512 x 2 fp32).

#define REP8(M) M(0) M(1) M(2) M(3) M(4) M(5) M(6) M(7)

#define DECL_ST(r) float4 st##r##_0, st##r##_1, st##r##_2, st##r##_3, st##r##_4;
#define LOAD_ST(r)                                                       \
  {                                                                      \
    const float* p = Whh + (size_t)(g + 64 * r) * KDIM + 64 * s;         \
    float4 a, b;                                                         \
    a = *(const float4*)(p + 0);  b = *(const float4*)(p + 4);           \
    st##r##_0 = pk4(a, b);                                               \
    a = *(const float4*)(p + 8);  b = *(const float4*)(p + 12);          \
    st##r##_1 = pk4(a, b);                                               \
    a = *(const float4*)(p + 16); b = *(const float4*)(p + 20);          \
    st##r##_2 = pk4(a, b);                                               \
    a = *(const float4*)(p + 24); b = *(const float4*)(p + 28);          \
    st##r##_3 = pk4(a, b);                                               \
    a = *(const float4*)(p + 32); b = *(const float4*)(p + 36);          \
    st##r##_4 = pk4(a, b);                                               \
  }

#define DECL_BA(r) float4 bA##r;
#define DECL_BB(r) float4 bB##r;
#define ISSUE_A(r) bA##r = cp[r];
#define ISSUE_B(r) bB##r = cp[r];

#define FD(r, u, hv)                                   \
  acc##r = fdot2f(st##r##_##u.x, hv.x, acc##r);        \
  acc##r = fdot2f(st##r##_##u.y, hv.y, acc##r);        \
  acc##r = fdot2f(st##r##_##u.z, hv.z, acc##r);        \
  acc##r = fdot2f(st##r##_##u.w, hv.w, acc##r);

#define DOT_ST(u)                                      \
  {                                                    \
    float4 hv = *(const float4*)(hc + 16 * u);         \
    FD(0, u, hv) FD(1, u, hv) FD(2, u, hv) FD(3, u, hv)\
    FD(4, u, hv) FD(5, u, hv) FD(6, u, hv) FD(7, u, hv)\
  }

#define FDB(r, B, hv)                                  \
  acc##r = fdot2f(B##r.x, hv.x, acc##r);               \
  acc##r = fdot2f(B##r.y, hv.y, acc##r);               \
  acc##r = fdot2f(B##r.z, hv.z, acc##r);               \
  acc##r = fdot2f(B##r.w, hv.w, acc##r);

#define DOT_BUF(B, u)                                      \
  {                                                        \
    float4 hv = *(const float4*)(hc + 16 * u);             \
    FDB(0, B, hv) FDB(1, B, hv) FDB(2, B, hv) FDB(3, B, hv)\
    FDB(4, B, hv) FDB(5, B, hv) FDB(6, B, hv) FDB(7, B, hv)\
  }

#define XOR_DPP(v, ctrl)                                              \
  (v + __int_as_float(__builtin_amdgcn_mov_dpp(__float_as_int(v),     \
                                               ctrl, 0xf, 0xf, true)))

__global__ __launch_bounds__(512, 2) void rnn_scan(const float* __restrict__ Whh,
                                                   const float4* __restrict__ ws,
                                                   float* __restrict__ io) {
  __shared__ __align__(16) char ldsm[2 * 1152 + 4096];
  const int tid = threadIdx.x;
  const int b = blockIdx.x;
  const int l = tid & 63;
  const int w = tid >> 6;
  const int s = l & 7;
  const int g = (l >> 3) | (w << 3);

  // static W: 8 rows x 40 cols as fp16 in 160 named VGPRs
  REP8(DECL_ST)
  REP8(LOAD_ST)
  REP8(DECL_BA)
  REP8(DECL_BB)

  // streamed-W chunk pointers (layout [c][w][l][r], float4 units)
  const float4* c0 = ws + (size_t)(w * 64 + l) * 8;
  const float4* c1 = c0 + 4096;
  const float4* c2 = c0 + 8192;

  // zero h buffer 0
  if (tid < 288) ((unsigned int*)ldsm)[tid] = 0u;
  __syncthreads();

  float* P = (float*)(ldsm + 2 * 1152);
  const int hb = (l >> 2) & 1;  // which k-half this quad holds after DPP reduce
  const bool pw = (l & 3) == 0;
  float* iorow = io + (size_t)b * HDIM;

  for (int t = 0; t < SEQ_T; ++t) {
    const char* hc = ldsm + (t & 1) * 1152 + s * 144;
    char* hn_base = ldsm + ((t & 1) ^ 1) * 1152;

    float uin = iorow[tid];  // prefetch this step's xw value (combine uses it)

    float acc0 = 0.f, acc1 = 0.f, acc2 = 0.f, acc3 = 0.f;
    float acc4 = 0.f, acc5 = 0.f, acc6 = 0.f, acc7 = 0.f;

    { const float4* cp = c0; REP8(ISSUE_A) }
    DOT_ST(0) DOT_ST(1) DOT_ST(2)
    { const float4* cp = c1; REP8(ISSUE_B) }
    DOT_ST(3) DOT_ST(4)
    DOT_BUF(bA, 5)
    { const float4* cp = c2; REP8(ISSUE_A) }
    DOT_BUF(bB, 6)
    DOT_BUF(bA, 7)

    // reduce k within quads: xor1 (quad_perm 0xB1=177), xor2 (0x4E=78)
    acc0 = XOR_DPP(acc0, 177); acc0 = XOR_DPP(acc0, 78);
    acc1 = XOR_DPP(acc1, 177); acc1 = XOR_DPP(acc1, 78);
    acc2 = XOR_DPP(acc2, 177); acc2 = XOR_DPP(acc2, 78);
    acc3 = XOR_DPP(acc3, 177); acc3 = XOR_DPP(acc3, 78);
    acc4 = XOR_DPP(acc4, 177); acc4 = XOR_DPP(acc4, 78);
    acc5 = XOR_DPP(acc5, 177); acc5 = XOR_DPP(acc5, 78);
    acc6 = XOR_DPP(acc6, 177); acc6 = XOR_DPP(acc6, 78);
    acc7 = XOR_DPP(acc7, 177); acc7 = XOR_DPP(acc7, 78);

    if (pw) {  // quad leaders write their half-sums (conflict-free banks)
      P[(g + 64 * 0) * 2 + hb] = acc0;
      P[(g + 64 * 1) * 2 + hb] = acc1;
      P[(g + 64 * 2) * 2 + hb] = acc2;
      P[(g + 64 * 3) * 2 + hb] = acc3;
      P[(g + 64 * 4) * 2 + hb] = acc4;
      P[(g + 64 * 5) * 2 + hb] = acc5;
      P[(g + 64 * 6) * 2 + hb] = acc6;
      P[(g + 64 * 7) * 2 + hb] = acc7;
    }
    __syncthreads();

    // combine: thread tid owns row tid
    float2 pp = *(const float2*)(P + tid * 2);
    float z = uin + pp.x + pp.y;
    float e = __expf(2.0f * z);
    float hn = 1.0f - 2.0f / (e + 1.0f);  // tanh(z)
    iorow[tid] = hn;
    *(_Float16*)(hn_base + (tid >> 6) * 144 + (tid & 63) * 2) = (_Float16)hn;
    __syncthreads();

    iorow += (size_t)BATCH * HDIM;
  }
}

extern "C" void kernel_launch(void* const* d_in, const int* in_sizes, int n_in,
                              void* d_out, int out_size, void* d_ws, size_t ws_size,
                              hipStream_t stream) {
  const float* x = (const float*)d_in[0];
  const float* Wih = (const float*)d_in[1];
  const float* Whh = (const float*)d_in[2];
  const float* bih = (const float*)d_in[3];
  const float* bhh = (const float*)d_in[4];
  float* out = (float*)d_out;
  float4* ws = (float4*)d_ws;

  w_prep<<<48, 256, 0, stream>>>(Whh, ws);

  const int M = SEQ_T * BATCH;
  dim3 g1((M / BM) * (HDIM / BN));
  xw_gemm<<<g1, 256, 0, stream>>>(x, Wih, bih, bhh, out);

  rnn_scan<<<BATCH, 512, 0, stream>>>(Whh, ws, out);
}

// Round 4
// 4310.929 us; speedup vs baseline: 9.0847x; 2.0034x over previous
//
#include <hip/hip_runtime.h>
#include <cmath>

// RNN: T=2048, B=64, I=H=512, fp32 in/out.
// Phase 1: xw_gemm — xw = x @ W_ih^T + (b_ih+b_hh) -> d_out [T*B, H] (fp32).
// Phase 2: rnn_scan — 64 WGs (1/batch) x 512 thr.
//   Per thread: 8 rows x 64-col slice of W_hh (fp16).
//     - cols [64s, 64s+48): 48 named fp16x8 regs (192 VGPRs), forced resident
//       via amdgpu_waves_per_eu(2,2).
//     - cols [64s+48, 64s+64): LDS (128 KB, per-thread 272B-strided, fills all
//       32 banks uniformly -> conflict-free-equivalent).
//   h triple-buffered fp16 in LDS -> ONE barrier/step. Full k-reduce in-wave:
//   DPP quad-perm xor1/xor2 + shfl_xor(4); lane (s,g) finalizes row g+64s.

#define SEQ_T 2048
#define BATCH 64
#define KDIM 512
#define HDIM 512

typedef _Float16 h2v __attribute__((ext_vector_type(2)));

static __device__ __forceinline__ float fdot2f(float wv, float hv, float acc) {
  return __builtin_amdgcn_fdot2(__builtin_bit_cast(h2v, wv),
                                __builtin_bit_cast(h2v, hv), acc, false);
}
static __device__ __forceinline__ float pkh(float a, float b) {
  return __builtin_bit_cast(float, __builtin_amdgcn_cvt_pkrtz(a, b));
}
static __device__ __forceinline__ float4 pk4(float4 a, float4 b) {
  return make_float4(pkh(a.x, a.y), pkh(a.z, a.w), pkh(b.x, b.y), pkh(b.z, b.w));
}

// ================= Phase 1: tiled fp32 GEMM (unchanged) =====================
#define BM 128
#define BN 64
#define BK 32
#define LDA_T (BM + 4)
#define LDB_T (BN + 4)

__global__ __launch_bounds__(256) void xw_gemm(const float* __restrict__ x,
                                               const float* __restrict__ Wih,
                                               const float* __restrict__ bih,
                                               const float* __restrict__ bhh,
                                               float* __restrict__ out) {
  __shared__ float As[BK * LDA_T];
  __shared__ float Bs[BK * LDB_T];
  const int tid = threadIdx.x;
  const int nb = blockIdx.x & 7;
  const int mb = blockIdx.x >> 3;
  const int m0 = mb * BM;
  const int n0 = nb * BN;
  const int tx = tid & 15;
  const int ty = tid >> 4;

  float acc[8][4];
#pragma unroll
  for (int i = 0; i < 8; ++i)
#pragma unroll
    for (int j = 0; j < 4; ++j) acc[i][j] = 0.f;

  for (int k0 = 0; k0 < KDIM; k0 += BK) {
#pragma unroll
    for (int p = 0; p < 4; ++p) {
      int idx = tid + p * 256;
      int r = idx >> 3, c = idx & 7;
      float4 a = *(const float4*)(x + (size_t)(m0 + r) * KDIM + k0 + c * 4);
      As[(c * 4 + 0) * LDA_T + r] = a.x;
      As[(c * 4 + 1) * LDA_T + r] = a.y;
      As[(c * 4 + 2) * LDA_T + r] = a.z;
      As[(c * 4 + 3) * LDA_T + r] = a.w;
    }
#pragma unroll
    for (int p = 0; p < 2; ++p) {
      int idx = tid + p * 256;
      int r = idx >> 3, c = idx & 7;
      float4 bv = *(const float4*)(Wih + (size_t)(n0 + r) * KDIM + k0 + c * 4);
      Bs[(c * 4 + 0) * LDB_T + r] = bv.x;
      Bs[(c * 4 + 1) * LDB_T + r] = bv.y;
      Bs[(c * 4 + 2) * LDB_T + r] = bv.z;
      Bs[(c * 4 + 3) * LDB_T + r] = bv.w;
    }
    __syncthreads();
#pragma unroll
    for (int kk = 0; kk < BK; ++kk) {
      float4 a0 = *(const float4*)(As + kk * LDA_T + ty * 8);
      float4 a1 = *(const float4*)(As + kk * LDA_T + ty * 8 + 4);
      float4 b0 = *(const float4*)(Bs + kk * LDB_T + tx * 4);
      float am[8] = {a0.x, a0.y, a0.z, a0.w, a1.x, a1.y, a1.z, a1.w};
      float bn_[4] = {b0.x, b0.y, b0.z, b0.w};
#pragma unroll
      for (int i = 0; i < 8; ++i)
#pragma unroll
        for (int j = 0; j < 4; ++j) acc[i][j] = fmaf(am[i], bn_[j], acc[i][j]);
    }
    __syncthreads();
  }

  float4 bi = *(const float4*)(bih + n0 + tx * 4);
  float4 bh = *(const float4*)(bhh + n0 + tx * 4);
  const float b0 = bi.x + bh.x, b1 = bi.y + bh.y, b2 = bi.z + bh.z, b3 = bi.w + bh.w;
#pragma unroll
  for (int i = 0; i < 8; ++i) {
    float4 v = make_float4(acc[i][0] + b0, acc[i][1] + b1, acc[i][2] + b2, acc[i][3] + b3);
    *(float4*)(out + (size_t)(m0 + ty * 8 + i) * HDIM + n0 + tx * 4) = v;
  }
}

// ================= Phase 2: recurrence ======================================
#define REP8(M) M(0) M(1) M(2) M(3) M(4) M(5) M(6) M(7)

#define DECL_ST(r) float4 st##r##_0, st##r##_1, st##r##_2, st##r##_3, st##r##_4, st##r##_5;
#define LOAD_ST(r)                                                   \
  {                                                                  \
    const float* p = Whh + (size_t)(g + 64 * r) * KDIM + 64 * s;     \
    float4 a, b;                                                     \
    a = *(const float4*)(p + 0);  b = *(const float4*)(p + 4);       \
    st##r##_0 = pk4(a, b);                                           \
    a = *(const float4*)(p + 8);  b = *(const float4*)(p + 12);      \
    st##r##_1 = pk4(a, b);                                           \
    a = *(const float4*)(p + 16); b = *(const float4*)(p + 20);      \
    st##r##_2 = pk4(a, b);                                           \
    a = *(const float4*)(p + 24); b = *(const float4*)(p + 28);      \
    st##r##_3 = pk4(a, b);                                           \
    a = *(const float4*)(p + 32); b = *(const float4*)(p + 36);      \
    st##r##_4 = pk4(a, b);                                           \
    a = *(const float4*)(p + 40); b = *(const float4*)(p + 44);      \
    st##r##_5 = pk4(a, b);                                           \
  }

#define FILL_WL(r)                                                   \
  {                                                                  \
    const float* p = Whh + (size_t)(g + 64 * r) * KDIM + 64 * s + 48;\
    float4 a, b;                                                     \
    a = *(const float4*)(p + 0); b = *(const float4*)(p + 4);        \
    wlp[2 * r] = pk4(a, b);                                          \
    a = *(const float4*)(p + 8); b = *(const float4*)(p + 12);       \
    wlp[2 * r + 1] = pk4(a, b);                                      \
  }

#define D4(A, W, H)            \
  A = fdot2f(W.x, H.x, A);     \
  A = fdot2f(W.y, H.y, A);     \
  A = fdot2f(W.z, H.z, A);     \
  A = fdot2f(W.w, H.w, A);

// phase A: h cols [0,32) of slice; phase B: [32,48) static + [48,64) LDS
#define PHA(r) D4(acc##r, st##r##_0, hva) D4(acc##r, st##r##_1, hvb) \
               D4(acc##r, st##r##_2, hvc) D4(acc##r, st##r##_3, hvd)
#define PHB(r, W0, W1) D4(acc##r, st##r##_4, hva) D4(acc##r, st##r##_5, hvb) \
                       D4(acc##r, W0, hvc) D4(acc##r, W1, hvd)

#define XOR_DPP(v, ctrl)                                              \
  (v + __int_as_float(__builtin_amdgcn_mov_dpp(__float_as_int(v),     \
                                               ctrl, 0xf, 0xf, true)))
#define REDUCE(r)                          \
  acc##r = XOR_DPP(acc##r, 177);           \
  acc##r = XOR_DPP(acc##r, 78);            \
  acc##r += __shfl_xor(acc##r, 4);

#define HB_BYTES 1152          // 8 slices * 144 B
#define WL_BASE (3 * HB_BYTES) // 3456
#define WL_STRIDE 272
#define LDS_TOTAL (WL_BASE + 512 * WL_STRIDE)  // 142720

__global__ __attribute__((amdgpu_flat_work_group_size(512, 512),
                          amdgpu_waves_per_eu(2, 2)))
void rnn_scan(const float* __restrict__ Whh, float* __restrict__ io) {
  extern __shared__ __align__(16) char ldsm[];
  const int tid = threadIdx.x;
  const int b = blockIdx.x;
  const int l = tid & 63;
  const int w = tid >> 6;
  const int s = l & 7;
  const int g = (l >> 3) | (w << 3);
  const int j = g + 64 * s;  // the row this lane finalizes

  // static W: 8 rows x 48 cols fp16 in 192 named VGPRs
  REP8(DECL_ST)
  REP8(LOAD_ST)

  // LDS W: 8 rows x 16 cols fp16, per-thread contiguous, 272B stride
  float4* wlp = (float4*)(ldsm + WL_BASE + tid * WL_STRIDE);
  REP8(FILL_WL)

  // zero h buffer 0
  if (tid < HB_BYTES / 4) ((unsigned int*)ldsm)[tid] = 0u;
  __syncthreads();

  const char* hcur = ldsm;
  char* hnxt = ldsm + HB_BYTES;
  char* hthr = ldsm + 2 * HB_BYTES;

  const bool sb0 = (s & 1), sb1 = (s & 2), sb2 = (s & 4);
  float* iorow = io + (size_t)b * HDIM;

  for (int t = 0; t < SEQ_T; ++t) {
    float uin = iorow[j];  // issue early; consumed after the dot

    const float4* hc4 = (const float4*)(hcur + s * 144);

    float acc0 = 0.f, acc1 = 0.f, acc2 = 0.f, acc3 = 0.f;
    float acc4 = 0.f, acc5 = 0.f, acc6 = 0.f, acc7 = 0.f;

    // ---- phase A: h[0..32) of this slice
    float4 hva = hc4[0], hvb = hc4[1], hvc = hc4[2], hvd = hc4[3];
    PHA(0) PHA(1) PHA(2) PHA(3) PHA(4) PHA(5) PHA(6) PHA(7)

    // ---- phase B: h[32..64); W cols 32..48 static, 48..64 from LDS
    hva = hc4[4]; hvb = hc4[5]; hvc = hc4[6]; hvd = hc4[7];
    float4 wA0 = wlp[0], wA1 = wlp[1];
    float4 wB0 = wlp[2], wB1 = wlp[3];
    PHB(0, wA0, wA1)
    wA0 = wlp[4]; wA1 = wlp[5];
    PHB(1, wB0, wB1)
    wB0 = wlp[6]; wB1 = wlp[7];
    PHB(2, wA0, wA1)
    wA0 = wlp[8]; wA1 = wlp[9];
    PHB(3, wB0, wB1)
    wB0 = wlp[10]; wB1 = wlp[11];
    PHB(4, wA0, wA1)
    wA0 = wlp[12]; wA1 = wlp[13];
    PHB(5, wB0, wB1)
    wB0 = wlp[14]; wB1 = wlp[15];
    PHB(6, wA0, wA1)
    PHB(7, wB0, wB1)

    // ---- full k-reduce in-wave (bits 0,1 via DPP quad-perm; bit 2 via shfl)
    REDUCE(0) REDUCE(1) REDUCE(2) REDUCE(3)
    REDUCE(4) REDUCE(5) REDUCE(6) REDUCE(7)

    // lane (s,g) finalizes row j = g + 64*s  ->  pick acc[s]
    float a01 = sb0 ? acc1 : acc0, a23 = sb0 ? acc3 : acc2;
    float a45 = sb0 ? acc5 : acc4, a67 = sb0 ? acc7 : acc6;
    float b01 = sb1 ? a23 : a01, b23 = sb1 ? a67 : a45;
    float tsel = sb2 ? b23 : b01;

    float z = uin + tsel;
    float e = __expf(2.0f * z);
    float hn = 1.0f - 2.0f * __builtin_amdgcn_rcpf(e + 1.0f);  // tanh(z)
    iorow[j] = hn;
    *(_Float16*)(hnxt + s * 144 + g * 2) = (_Float16)hn;

    // rotate triple buffer; ONE barrier per step
    char* tmp = (char*)hcur;
    hcur = hnxt; hnxt = hthr; hthr = tmp;
    iorow += (size_t)BATCH * HDIM;
    __syncthreads();
  }
}

extern "C" void kernel_launch(void* const* d_in, const int* in_sizes, int n_in,
                              void* d_out, int out_size, void* d_ws, size_t ws_size,
                              hipStream_t stream) {
  const float* x = (const float*)d_in[0];
  const float* Wih = (const float*)d_in[1];
  const float* Whh = (const float*)d_in[2];
  const float* bih = (const float*)d_in[3];
  const float* bhh = (const float*)d_in[4];
  float* out = (float*)d_out;

  static int lds_attr_set = 0;  // idempotent runtime attr (not a stream op)
  hipFuncSetAttribute((const void*)rnn_scan,
                      hipFuncAttributeMaxDynamicSharedMemorySize, LDS_TOTAL);
  (void)lds_attr_set;

  const int M = SEQ_T * BATCH;
  dim3 g1((M / BM) * (HDIM / BN));
  xw_gemm<<<g1, 256, 0, stream>>>(x, Wih, bih, bhh, out);

  rnn_scan<<<BATCH, 512, LDS_TOTAL, stream>>>(Whh, out);
}

// Round 6
// 3997.672 us; speedup vs baseline: 9.7966x; 1.0784x over previous
//
#include <hip/hip_runtime.h>
#include <cmath>

// RNN: T=2048, B=64, I=H=512, fp32 in/out.
// Phase 1: xw_gemm — xw = x @ W_ih^T + (b_ih+b_hh) -> d_out [T*B, H] (fp32).
// Phase 2: rnn_scan — 64 WGs (1/batch) x 512 thr, MFMA-based GEMV:
//   D = A*B with A = h-chunk replicated over all 16 rows (lane value depends
//   only on lane-group) -> D rows identical -> zero cross-lane reduce.
//   B = W^T fragments (fp16): 13 k-chunks in regs/AGPRs (208 regs), 3 chunks
//   in LDS (96 KB). 64 mfma/wave/step. h triple-buffered fp16 in LDS,
//   ONE barrier/step.

#define SEQ_T 2048
#define BATCH 64
#define KDIM 512
#define HDIM 512

typedef __fp16 h2v __attribute__((ext_vector_type(2)));
typedef __fp16 f16x8 __attribute__((ext_vector_type(8)));
typedef float f32x4 __attribute__((ext_vector_type(4)));

static __device__ __forceinline__ f16x8 pk8(float4 a, float4 b) {
  h2v p0 = __builtin_amdgcn_cvt_pkrtz(a.x, a.y);
  h2v p1 = __builtin_amdgcn_cvt_pkrtz(a.z, a.w);
  h2v p2 = __builtin_amdgcn_cvt_pkrtz(b.x, b.y);
  h2v p3 = __builtin_amdgcn_cvt_pkrtz(b.z, b.w);
  f16x8 r;
  r[0] = p0[0]; r[1] = p0[1]; r[2] = p1[0]; r[3] = p1[1];
  r[4] = p2[0]; r[5] = p2[1]; r[6] = p3[0]; r[7] = p3[1];
  return r;
}

// ================= Phase 1: tiled fp32 GEMM (unchanged) =====================
#define BM 128
#define BN 64
#define BK 32
#define LDA_T (BM + 4)
#define LDB_T (BN + 4)

__global__ __launch_bounds__(256) void xw_gemm(const float* __restrict__ x,
                                               const float* __restrict__ Wih,
                                               const float* __restrict__ bih,
                                               const float* __restrict__ bhh,
                                               float* __restrict__ out) {
  __shared__ float As[BK * LDA_T];
  __shared__ float Bs[BK * LDB_T];
  const int tid = threadIdx.x;
  const int nb = blockIdx.x & 7;
  const int mb = blockIdx.x >> 3;
  const int m0 = mb * BM;
  const int n0 = nb * BN;
  const int tx = tid & 15;
  const int ty = tid >> 4;

  float acc[8][4];
#pragma unroll
  for (int i = 0; i < 8; ++i)
#pragma unroll
    for (int j = 0; j < 4; ++j) acc[i][j] = 0.f;

  for (int k0 = 0; k0 < KDIM; k0 += BK) {
#pragma unroll
    for (int p = 0; p < 4; ++p) {
      int idx = tid + p * 256;
      int r = idx >> 3, c = idx & 7;
      float4 a = *(const float4*)(x + (size_t)(m0 + r) * KDIM + k0 + c * 4);
      As[(c * 4 + 0) * LDA_T + r] = a.x;
      As[(c * 4 + 1) * LDA_T + r] = a.y;
      As[(c * 4 + 2) * LDA_T + r] = a.z;
      As[(c * 4 + 3) * LDA_T + r] = a.w;
    }
#pragma unroll
    for (int p = 0; p < 2; ++p) {
      int idx = tid + p * 256;
      int r = idx >> 3, c = idx & 7;
      float4 bv = *(const float4*)(Wih + (size_t)(n0 + r) * KDIM + k0 + c * 4);
      Bs[(c * 4 + 0) * LDB_T + r] = bv.x;
      Bs[(c * 4 + 1) * LDB_T + r] = bv.y;
      Bs[(c * 4 + 2) * LDB_T + r] = bv.z;
      Bs[(c * 4 + 3) * LDB_T + r] = bv.w;
    }
    __syncthreads();
#pragma unroll
    for (int kk = 0; kk < BK; ++kk) {
      float4 a0 = *(const float4*)(As + kk * LDA_T + ty * 8);
      float4 a1 = *(const float4*)(As + kk * LDA_T + ty * 8 + 4);
      float4 b0 = *(const float4*)(Bs + kk * LDB_T + tx * 4);
      float am[8] = {a0.x, a0.y, a0.z, a0.w, a1.x, a1.y, a1.z, a1.w};
      float bn_[4] = {b0.x, b0.y, b0.z, b0.w};
#pragma unroll
      for (int i = 0; i < 8; ++i)
#pragma unroll
        for (int j = 0; j < 4; ++j) acc[i][j] = fmaf(am[i], bn_[j], acc[i][j]);
    }
    __syncthreads();
  }

  float4 bi = *(const float4*)(bih + n0 + tx * 4);
  float4 bh = *(const float4*)(bhh + n0 + tx * 4);
  const float b0 = bi.x + bh.x, b1 = bi.y + bh.y, b2 = bi.z + bh.z, b3 = bi.w + bh.w;
#pragma unroll
  for (int i = 0; i < 8; ++i) {
    float4 v = make_float4(acc[i][0] + b0, acc[i][1] + b1, acc[i][2] + b2, acc[i][3] + b3);
    *(float4*)(out + (size_t)(m0 + ty * 8 + i) * HDIM + n0 + tx * 4) = v;
  }
}

// ================= Phase 2: MFMA recurrence =================================
// wave w owns rows [64w, 64w+64). Lane l: m16 = l&15 (B col / W row-in-block),
// gh = l>>4 (k lane-group). B-frag(c,n): W[64w+16c+m16][32n+8gh+e], e=0..7.
// A-frag(n): h[32n+8gh+e] (same for all 16 rows -> D rows identical).
// D extract (m89-verified map: col=lane&15): z[64w+16c+m16] = dc[any reg].

#define REPB(M, c) M(c,0) M(c,1) M(c,2) M(c,3) M(c,4) M(c,5) M(c,6) \
                   M(c,7) M(c,8) M(c,9) M(c,10) M(c,11) M(c,12)

#define DECLB(c, n) f16x8 bf##c##_##n;
#define LOADB(c, n)                                        \
  {                                                        \
    const float* p = wr##c + 32 * n;                       \
    bf##c##_##n = pk8(*(const float4*)p, *(const float4*)(p + 4)); \
  }
#define STOREB(c, n)                                                        \
  {                                                                         \
    const float* p = wr##c + 32 * n;                                        \
    *(f16x8*)(ldsm + ((n - 13) * 4 + c) * 8192 + (tid << 4)) =              \
        pk8(*(const float4*)p, *(const float4*)(p + 4));                    \
  }

#define MF(c, n) \
  d##c = __builtin_amdgcn_mfma_f32_16x16x32_f16(acur, bf##c##_##n, d##c, 0, 0, 0);
#define MFL(c, n)                                                           \
  {                                                                         \
    f16x8 bl = *(const f16x8*)(ldsm + ((n - 13) * 4 + c) * 8192 + (tid << 4)); \
    d##c = __builtin_amdgcn_mfma_f32_16x16x32_f16(acur, bl, d##c, 0, 0, 0); \
  }

// one k-chunk: 4 mfmas with current A-frag, prefetch next A-frag
#define CH(n, nn)                                                \
  {                                                              \
    f16x8 anx = *(const f16x8*)(hcv + 64 * (nn) + goff);         \
    MF(0, n) MF(1, n) MF(2, n) MF(3, n)                          \
    acur = anx;                                                  \
  }
#define CHL(n, nn)                                               \
  {                                                              \
    f16x8 anx = *(const f16x8*)(hcv + 64 * (nn) + goff);         \
    MFL(0, n) MFL(1, n) MFL(2, n) MFL(3, n)                      \
    acur = anx;                                                  \
  }

#define WLDS_BYTES (12 * 8192)             // 98304
#define HBUF0 WLDS_BYTES
#define LDS_TOTAL (WLDS_BYTES + 3 * 1024)  // 101376

__global__ __attribute__((amdgpu_flat_work_group_size(512, 512),
                          amdgpu_waves_per_eu(2, 2)))
void rnn_scan(const float* __restrict__ Whh, float* __restrict__ io) {
  extern __shared__ __align__(16) char ldsm[];
  const int tid = threadIdx.x;
  const int b = blockIdx.x;
  const int l = tid & 63;
  const int w = tid >> 6;
  const int m16 = l & 15;
  const int gh = l >> 4;
  const int goff = gh << 4;   // byte offset of this lane-group's 16B in a chunk
  const int rb = w << 6;      // wave's first row
  const int jo = rb + l;      // the row this lane finalizes

  const float* wr0 = Whh + (size_t)(rb + 0 + m16) * KDIM + 8 * gh;
  const float* wr1 = Whh + (size_t)(rb + 16 + m16) * KDIM + 8 * gh;
  const float* wr2 = Whh + (size_t)(rb + 32 + m16) * KDIM + 8 * gh;
  const float* wr3 = Whh + (size_t)(rb + 48 + m16) * KDIM + 8 * gh;

  // 13 k-chunks x 4 row-blocks resident in regs/AGPRs (208 regs)
  REPB(DECLB, 0) REPB(DECLB, 1) REPB(DECLB, 2) REPB(DECLB, 3)
  REPB(LOADB, 0) REPB(LOADB, 1) REPB(LOADB, 2) REPB(LOADB, 3)

  // 3 k-chunks x 4 row-blocks in LDS (96 KB)
  STOREB(0, 13) STOREB(1, 13) STOREB(2, 13) STOREB(3, 13)
  STOREB(0, 14) STOREB(1, 14) STOREB(2, 14) STOREB(3, 14)
  STOREB(0, 15) STOREB(1, 15) STOREB(2, 15) STOREB(3, 15)

  // zero h buffer 0 (fp16[512])
  if (tid < 512) ((unsigned short*)(ldsm + HBUF0))[tid] = 0;
  __syncthreads();

  char* hcur = ldsm + HBUF0;
  char* hnxt = ldsm + HBUF0 + 1024;
  char* hthr = ldsm + HBUF0 + 2048;

  float* iorow = io + (size_t)b * HDIM;

  for (int t = 0; t < SEQ_T; ++t) {
    float uin = iorow[jo];  // global prefetch, consumed in the tail

    const char* hcv = hcur;
    f16x8 acur = *(const f16x8*)(hcv + goff);  // chunk 0 A-frag

    f32x4 d0 = {0.f, 0.f, 0.f, 0.f};
    f32x4 d1 = {0.f, 0.f, 0.f, 0.f};
    f32x4 d2 = {0.f, 0.f, 0.f, 0.f};
    f32x4 d3 = {0.f, 0.f, 0.f, 0.f};

    CH(0, 1)  CH(1, 2)  CH(2, 3)  CH(3, 4)  CH(4, 5)  CH(5, 6)  CH(6, 7)
    CH(7, 8)  CH(8, 9)  CH(9, 10) CH(10, 11) CH(11, 12) CH(12, 13)
    CHL(13, 14) CHL(14, 15) CHL(15, 15)

    // D rows identical -> reg 0 of acc c holds z[rb + 16c + m16].
    // lane l finalizes row jo = rb + l: select c = l>>4.
    float za = (l & 16) ? d1[0] : d0[0];
    float zb = (l & 16) ? d3[0] : d2[0];
    float zs = (l & 32) ? zb : za;

    float z = uin + zs;
    float e = __expf(2.0f * z);
    float hn = 1.0f - 2.0f * __builtin_amdgcn_rcpf(e + 1.0f);  // tanh(z)
    iorow[jo] = hn;
    *(__fp16*)(hnxt + 2 * jo) = (__fp16)hn;

    // rotate triple buffer; ONE barrier per step
    char* tmp = hcur;
    hcur = hnxt; hnxt = hthr; hthr = tmp;
    iorow += (size_t)BATCH * HDIM;
    __syncthreads();
  }
}

extern "C" void kernel_launch(void* const* d_in, const int* in_sizes, int n_in,
                              void* d_out, int out_size, void* d_ws, size_t ws_size,
                              hipStream_t stream) {
  const float* x = (const float*)d_in[0];
  const float* Wih = (const float*)d_in[1];
  const float* Whh = (const float*)d_in[2];
  const float* bih = (const float*)d_in[3];
  const float* bhh = (const float*)d_in[4];
  float* out = (float*)d_out;

  (void)hipFuncSetAttribute((const void*)rnn_scan,
                            hipFuncAttributeMaxDynamicSharedMemorySize,
                            LDS_TOTAL);

  const int M = SEQ_T * BATCH;
  dim3 g1((M / BM) * (HDIM / BN));
  xw_gemm<<<g1, 256, 0, stream>>>(x, Wih, bih, bhh, out);

  rnn_scan<<<BATCH, 512, LDS_TOTAL, stream>>>(Whh, out);
}

// Round 7
// 3358.463 us; speedup vs baseline: 11.6612x; 1.1903x over previous
//
#include <hip/hip_runtime.h>
#include <cmath>

// RNN: T=2048, B=64, I=H=512, fp32 in/out.
// Phase 1: xw_gemm — f16-MFMA GEMM: xw = x @ W_ih^T + (b_ih+b_hh) -> d_out.
// Phase 2: rnn_scan — 64 WGs (1/batch) x 512 thr, MFMA GEMV (replicated A):
//   W^T f16 fragments: 12 chunks register-intent (compiler keeps ~9, streams
//   rest from L2), 4 chunks in LDS (128 KB). 64 mfma/wave/step.
//   h triple-buffered fp16 in LDS, ONE barrier/step.

#define SEQ_T 2048
#define BATCH 64
#define KDIM 512
#define HDIM 512

typedef __fp16 h2v __attribute__((ext_vector_type(2)));
typedef __fp16 f16x8 __attribute__((ext_vector_type(8)));
typedef float f32x4 __attribute__((ext_vector_type(4)));

static __device__ __forceinline__ f16x8 pk8(float4 a, float4 b) {
  h2v p0 = __builtin_amdgcn_cvt_pkrtz(a.x, a.y);
  h2v p1 = __builtin_amdgcn_cvt_pkrtz(a.z, a.w);
  h2v p2 = __builtin_amdgcn_cvt_pkrtz(b.x, b.y);
  h2v p3 = __builtin_amdgcn_cvt_pkrtz(b.z, b.w);
  f16x8 r;
  r[0] = p0[0]; r[1] = p0[1]; r[2] = p1[0]; r[3] = p1[1];
  r[4] = p2[0]; r[5] = p2[1]; r[6] = p3[0]; r[7] = p3[1];
  return r;
}

// ================= Phase 1: f16 MFMA GEMM ===================================
// A = x [M][K] fp32 -> f16 LDS tile; B = W_ih [N][K] (B^T layout, k-contig).
// Tile BM=128 x BN=64 x BK=64, 4 waves (2m x 2n), 8 acc f32x4 per wave.
// LDS rows padded to 144 B (72 f16) -> even 8-way bank spread (floor).

#define G_LDA 72  // f16 units per row (144 B)

#define MFM(mt, nt) \
  d##mt##nt = __builtin_amdgcn_mfma_f32_16x16x32_f16(fa##mt, fb##nt, d##mt##nt, 0, 0, 0);

#define EPI(mt, nt, bb)                                                     \
  {                                                                         \
    int row = m0 + wm + mt * 16 + (l >> 4) * 4;                             \
    int col = n0 + wn + nt * 16 + (l & 15);                                 \
    out[(size_t)(row + 0) * HDIM + col] = d##mt##nt[0] + bb;                \
    out[(size_t)(row + 1) * HDIM + col] = d##mt##nt[1] + bb;                \
    out[(size_t)(row + 2) * HDIM + col] = d##mt##nt[2] + bb;                \
    out[(size_t)(row + 3) * HDIM + col] = d##mt##nt[3] + bb;                \
  }

__global__ __launch_bounds__(256) void xw_gemm(const float* __restrict__ x,
                                               const float* __restrict__ Wih,
                                               const float* __restrict__ bih,
                                               const float* __restrict__ bhh,
                                               float* __restrict__ out) {
  __shared__ __fp16 At[128 * G_LDA];
  __shared__ __fp16 Bt[64 * G_LDA];
  const int tid = threadIdx.x;
  const int l = tid & 63;
  const int w = tid >> 6;
  const int m0 = (blockIdx.x >> 3) * 128;
  const int n0 = (blockIdx.x & 7) * 64;
  const int wm = (w >> 1) * 64;
  const int wn = (w & 1) * 32;

  const float bias0 = bih[n0 + wn + (l & 15)] + bhh[n0 + wn + (l & 15)];
  const float bias1 = bih[n0 + wn + 16 + (l & 15)] + bhh[n0 + wn + 16 + (l & 15)];

  f32x4 d00 = {0,0,0,0}, d01 = {0,0,0,0}, d10 = {0,0,0,0}, d11 = {0,0,0,0};
  f32x4 d20 = {0,0,0,0}, d21 = {0,0,0,0}, d30 = {0,0,0,0}, d31 = {0,0,0,0};

  for (int k0 = 0; k0 < KDIM; k0 += 64) {
    __syncthreads();
    // stage A: 128x64 fp32 -> f16 (1024 16B units; 4 per thread)
#pragma unroll
    for (int p = 0; p < 4; ++p) {
      int idx = tid + p * 256;
      int r = idx >> 3, sg = idx & 7;
      const float* ps = x + (size_t)(m0 + r) * KDIM + k0 + sg * 8;
      *(f16x8*)(At + r * G_LDA + sg * 8) =
          pk8(*(const float4*)ps, *(const float4*)(ps + 4));
    }
    // stage B: 64x64 fp32 -> f16 (512 units; 2 per thread)
#pragma unroll
    for (int p = 0; p < 2; ++p) {
      int idx = tid + p * 256;
      int r = idx >> 3, sg = idx & 7;
      const float* ps = Wih + (size_t)(n0 + r) * KDIM + k0 + sg * 8;
      *(f16x8*)(Bt + r * G_LDA + sg * 8) =
          pk8(*(const float4*)ps, *(const float4*)(ps + 4));
    }
    __syncthreads();
#pragma unroll
    for (int kk = 0; kk < 2; ++kk) {
      const int kc = kk * 32 + (l >> 4) * 8;
      f16x8 fa0 = *(const f16x8*)(At + (wm + 0 * 16 + (l & 15)) * G_LDA + kc);
      f16x8 fa1 = *(const f16x8*)(At + (wm + 1 * 16 + (l & 15)) * G_LDA + kc);
      f16x8 fa2 = *(const f16x8*)(At + (wm + 2 * 16 + (l & 15)) * G_LDA + kc);
      f16x8 fa3 = *(const f16x8*)(At + (wm + 3 * 16 + (l & 15)) * G_LDA + kc);
      f16x8 fb0 = *(const f16x8*)(Bt + (wn + 0 * 16 + (l & 15)) * G_LDA + kc);
      f16x8 fb1 = *(const f16x8*)(Bt + (wn + 1 * 16 + (l & 15)) * G_LDA + kc);
      MFM(0, 0) MFM(1, 0) MFM(2, 0) MFM(3, 0)
      MFM(0, 1) MFM(1, 1) MFM(2, 1) MFM(3, 1)
    }
  }

  EPI(0, 0, bias0) EPI(1, 0, bias0) EPI(2, 0, bias0) EPI(3, 0, bias0)
  EPI(0, 1, bias1) EPI(1, 1, bias1) EPI(2, 1, bias1) EPI(3, 1, bias1)
}

// ================= Phase 2: MFMA recurrence =================================
// wave w owns rows [64w, 64w+64). Lane l: m16 = l&15 (B col / W row-in-block),
// gh = l>>4 (k lane-group). B-frag(c,n): W[64w+16c+m16][32n+8gh+e], e=0..7.
// A-frag(n): h[32n+8gh+e] replicated over rows -> D rows identical.
// Chunks 0..11: register-intent; chunks 12..15: LDS (4 x 32 KB).

#define REPB(M, c) M(c,0) M(c,1) M(c,2) M(c,3) M(c,4) M(c,5) \
                   M(c,6) M(c,7) M(c,8) M(c,9) M(c,10) M(c,11)

#define DECLB(c, n) f16x8 bf##c##_##n;
#define LOADB(c, n)                                        \
  {                                                        \
    const float* p = wr##c + 32 * n;                       \
    bf##c##_##n = pk8(*(const float4*)p, *(const float4*)(p + 4)); \
  }
#define STOREB(c, n)                                                        \
  {                                                                         \
    const float* p = wr##c + 32 * n;                                        \
    *(f16x8*)(ldsm + ((n - 12) * 4 + c) * 8192 + (tid << 4)) =              \
        pk8(*(const float4*)p, *(const float4*)(p + 4));                    \
  }

#define MF(c, n) \
  d##c = __builtin_amdgcn_mfma_f32_16x16x32_f16(acur, bf##c##_##n, d##c, 0, 0, 0);
#define MFL(c, n)                                                           \
  {                                                                         \
    f16x8 bl = *(const f16x8*)(ldsm + ((n - 12) * 4 + c) * 8192 + (tid << 4)); \
    d##c = __builtin_amdgcn_mfma_f32_16x16x32_f16(acur, bl, d##c, 0, 0, 0); \
  }

#define CH(n, nn)                                                \
  {                                                              \
    f16x8 anx = *(const f16x8*)(hcv + 64 * (nn) + goff);         \
    MF(0, n) MF(1, n) MF(2, n) MF(3, n)                          \
    acur = anx;                                                  \
  }
#define CHL(n, nn)                                               \
  {                                                              \
    f16x8 anx = *(const f16x8*)(hcv + 64 * (nn) + goff);         \
    MFL(0, n) MFL(1, n) MFL(2, n) MFL(3, n)                      \
    acur = anx;                                                  \
  }

#define WLDS_BYTES (16 * 8192)             // 131072 (4 chunks x 32 KB)
#define HBUF0 WLDS_BYTES
#define LDS_TOTAL (WLDS_BYTES + 3 * 1024)  // 134144

__global__ __attribute__((amdgpu_flat_work_group_size(512, 512),
                          amdgpu_waves_per_eu(2, 2)))
void rnn_scan(const float* __restrict__ Whh, float* __restrict__ io) {
  extern __shared__ __align__(16) char ldsm[];
  const int tid = threadIdx.x;
  const int b = blockIdx.x;
  const int l = tid & 63;
  const int w = tid >> 6;
  const int m16 = l & 15;
  const int gh = l >> 4;
  const int goff = gh << 4;
  const int rb = w << 6;
  const int jo = rb + l;

  const float* wr0 = Whh + (size_t)(rb + 0 + m16) * KDIM + 8 * gh;
  const float* wr1 = Whh + (size_t)(rb + 16 + m16) * KDIM + 8 * gh;
  const float* wr2 = Whh + (size_t)(rb + 32 + m16) * KDIM + 8 * gh;
  const float* wr3 = Whh + (size_t)(rb + 48 + m16) * KDIM + 8 * gh;

  // 12 k-chunks x 4 row-blocks register-intent
  REPB(DECLB, 0) REPB(DECLB, 1) REPB(DECLB, 2) REPB(DECLB, 3)
  REPB(LOADB, 0) REPB(LOADB, 1) REPB(LOADB, 2) REPB(LOADB, 3)

  // 4 k-chunks x 4 row-blocks in LDS (128 KB)
  STOREB(0, 12) STOREB(1, 12) STOREB(2, 12) STOREB(3, 12)
  STOREB(0, 13) STOREB(1, 13) STOREB(2, 13) STOREB(3, 13)
  STOREB(0, 14) STOREB(1, 14) STOREB(2, 14) STOREB(3, 14)
  STOREB(0, 15) STOREB(1, 15) STOREB(2, 15) STOREB(3, 15)

  if (tid < 512) ((unsigned short*)(ldsm + HBUF0))[tid] = 0;
  __syncthreads();

  char* hcur = ldsm + HBUF0;
  char* hnxt = ldsm + HBUF0 + 1024;
  char* hthr = ldsm + HBUF0 + 2048;

  float* iorow = io + (size_t)b * HDIM;

  for (int t = 0; t < SEQ_T; ++t) {
    float uin = iorow[jo];  // early issue; consumed in tail

    const char* hcv = hcur;
    f16x8 acur = *(const f16x8*)(hcv + goff);

    f32x4 d0 = {0.f, 0.f, 0.f, 0.f};
    f32x4 d1 = {0.f, 0.f, 0.f, 0.f};
    f32x4 d2 = {0.f, 0.f, 0.f, 0.f};
    f32x4 d3 = {0.f, 0.f, 0.f, 0.f};

    CH(0, 1)  CH(1, 2)  CH(2, 3)   CH(3, 4)   CH(4, 5)   CH(5, 6)
    CH(6, 7)  CH(7, 8)  CH(8, 9)   CH(9, 10)  CH(10, 11) CH(11, 12)
    CHL(12, 13) CHL(13, 14) CHL(14, 15) CHL(15, 15)

    float za = (l & 16) ? d1[0] : d0[0];
    float zb = (l & 16) ? d3[0] : d2[0];
    float zs = (l & 32) ? zb : za;

    float z = uin + zs;
    float e = __expf(2.0f * z);
    float hn = 1.0f - 2.0f * __builtin_amdgcn_rcpf(e + 1.0f);  // tanh(z)
    iorow[jo] = hn;
    *(__fp16*)(hnxt + 2 * jo) = (__fp16)hn;

    char* tmp = hcur;
    hcur = hnxt; hnxt = hthr; hthr = tmp;
    iorow += (size_t)BATCH * HDIM;
    __syncthreads();
  }
}

extern "C" void kernel_launch(void* const* d_in, const int* in_sizes, int n_in,
                              void* d_out, int out_size, void* d_ws, size_t ws_size,
                              hipStream_t stream) {
  const float* x = (const float*)d_in[0];
  const float* Wih = (const float*)d_in[1];
  const float* Whh = (const float*)d_in[2];
  const float* bih = (const float*)d_in[3];
  const float* bhh = (const float*)d_in[4];
  float* out = (float*)d_out;

  (void)hipFuncSetAttribute((const void*)rnn_scan,
                            hipFuncAttributeMaxDynamicSharedMemorySize,
                            LDS_TOTAL);

  const int M = SEQ_T * BATCH;
  dim3 g1((M / 128) * (HDIM / 64));  // 8192
  xw_gemm<<<g1, 256, 0, stream>>>(x, Wih, bih, bhh, out);

  rnn_scan<<<BATCH, 512, LDS_TOTAL, stream>>>(Whh, out);
}